// Round 1
// baseline (246.958 us; speedup 1.0000x reference)
//
#include <hip/hip_runtime.h>
#include <hip/hip_bf16.h>
#include <stdint.h>

#define DI __device__ __forceinline__

typedef __attribute__((ext_vector_type(8))) short bf16x8;
typedef __attribute__((ext_vector_type(4))) float f32x4;

static constexpr int Bx = 16, Cx = 512, Nx = 4096;

// async global->LDS, 16B per lane. LDS dst must be the WAVE-UNIFORM base;
// HW adds lane*16. Global src is per-lane.
DI void gload_lds16(const void* gsrc, void* ldst) {
  __builtin_amdgcn_global_load_lds(
      (const __attribute__((address_space(1))) uint32_t*)gsrc,
      (__attribute__((address_space(3))) uint32_t*)ldst, 16, 0, 0);
}

// ---------------------------------------------------------------------------
// Kernel 1: fp32 x -> bf16 Xb [B][C][N] and bf16 XbT [B][N][C]
// 64x64 tiles via LDS. grid (C/64, N/64, B), 256 threads.
// ---------------------------------------------------------------------------
__global__ __launch_bounds__(256) void k_cast_transpose(
    const float* __restrict__ x,
    __hip_bfloat16* __restrict__ xb,
    __hip_bfloat16* __restrict__ xbt) {
  __shared__ __hip_bfloat16 tile[64][65];
  const int b = blockIdx.z;
  const int c0 = blockIdx.x * 64;
  const int n0 = blockIdx.y * 64;
  const int t = threadIdx.x;
  const int r = t >> 2;          // 0..63
  const int q = (t & 3) * 16;    // 0,16,32,48

  const float* xp = x + ((size_t)b * Cx + (c0 + r)) * Nx + (n0 + q);
  alignas(16) __hip_bfloat16 v[16];
#pragma unroll
  for (int j = 0; j < 4; ++j) {
    float4 f = *(const float4*)(xp + j * 4);
    v[j * 4 + 0] = __float2bfloat16(f.x);
    v[j * 4 + 1] = __float2bfloat16(f.y);
    v[j * 4 + 2] = __float2bfloat16(f.z);
    v[j * 4 + 3] = __float2bfloat16(f.w);
  }
  // straight bf16 copy (row-major, coalesced 32B/lane)
  __hip_bfloat16* xbp = xb + ((size_t)b * Cx + (c0 + r)) * Nx + (n0 + q);
  *(uint4*)xbp = *(const uint4*)&v[0];
  *(uint4*)(xbp + 8) = *(const uint4*)&v[8];
#pragma unroll
  for (int j = 0; j < 16; ++j) tile[r][q + j] = v[j];
  __syncthreads();
  // transposed write: local n-row = r, c-cols = q..q+15
  alignas(16) __hip_bfloat16 o[16];
#pragma unroll
  for (int j = 0; j < 16; ++j) o[j] = tile[q + j][r];
  __hip_bfloat16* xtp = xbt + ((size_t)b * Nx + (n0 + r)) * Cx + (c0 + q);
  *(uint4*)xtp = *(const uint4*)&o[0];
  *(uint4*)(xtp + 8) = *(const uint4*)&o[8];
}

// ---------------------------------------------------------------------------
// NT bf16 GEMM, m97 structure: 128x128 tile, BK=32, 4 waves (2x2 of 64x64),
// global_load_lds(16B) staging, v_mfma_f32_16x16x32_bf16, fp32 out.
// A: [Z][M][K] row-major. Bt: [Z][Nd][K] row-major. C = A * Bt^T.
// EPI: out = xres + beta*acc (residual add), else raw fp32 store.
// ---------------------------------------------------------------------------
template <bool EPI>
__global__ __launch_bounds__(256) void k_gemm_nt(
    const __hip_bfloat16* A, const __hip_bfloat16* Bt,
    float* __restrict__ Co, const float* __restrict__ xres,
    const float* __restrict__ betap, int M, int Nd, int K) {
  __shared__ alignas(16) __hip_bfloat16 sA[128 * 32];
  __shared__ alignas(16) __hip_bfloat16 sB[128 * 32];

  const int t = threadIdx.x;
  const int lane = t & 63;
  const int wave = t >> 6;
  const int wr = (wave >> 1) * 64;  // wave row offset in tile
  const int wc = (wave & 1) * 64;   // wave col offset in tile
  const int fr = lane & 15;         // fragment row/col within 16
  const int fq = lane >> 4;         // k-quarter (0..3)

  const int z = blockIdx.z;
  const size_t aBase = (size_t)z * M * K + (size_t)(blockIdx.x * 128) * K;
  const size_t bBase = (size_t)z * Nd * K + (size_t)(blockIdx.y * 128) * K;

  const int srow = t >> 2;         // staging row 0..63 (+64 for 2nd issue)
  const int skoff = (t & 3) * 8;   // staging k-offset (elements)
  char* sAb = (char*)sA + (wave << 10);  // wave-uniform LDS byte base
  char* sBb = (char*)sB + (wave << 10);

  f32x4 acc[4][4];
#pragma unroll
  for (int m = 0; m < 4; ++m)
#pragma unroll
    for (int n = 0; n < 4; ++n) acc[m][n] = {0.f, 0.f, 0.f, 0.f};

  for (int kt = 0; kt < K; kt += 32) {
    gload_lds16(A + aBase + (size_t)srow * K + kt + skoff, sAb);
    gload_lds16(A + aBase + (size_t)(srow + 64) * K + kt + skoff, sAb + 4096);
    gload_lds16(Bt + bBase + (size_t)srow * K + kt + skoff, sBb);
    gload_lds16(Bt + bBase + (size_t)(srow + 64) * K + kt + skoff, sBb + 4096);
    __syncthreads();  // implies s_waitcnt vmcnt(0) before s_barrier

    bf16x8 af[4], bfr[4];
#pragma unroll
    for (int m = 0; m < 4; ++m)
      af[m] = *(const bf16x8*)&sA[(wr + m * 16 + fr) * 32 + fq * 8];
#pragma unroll
    for (int n = 0; n < 4; ++n)
      bfr[n] = *(const bf16x8*)&sB[(wc + n * 16 + fr) * 32 + fq * 8];
#pragma unroll
    for (int m = 0; m < 4; ++m)
#pragma unroll
      for (int n = 0; n < 4; ++n)
        acc[m][n] = __builtin_amdgcn_mfma_f32_16x16x32_bf16(af[m], bfr[n],
                                                            acc[m][n], 0, 0, 0);
    __syncthreads();
  }

  const float beta = EPI ? betap[0] : 0.f;
  float* cb = Co + (size_t)z * M * Nd;
#pragma unroll
  for (int m = 0; m < 4; ++m) {
#pragma unroll
    for (int n = 0; n < 4; ++n) {
#pragma unroll
      for (int r = 0; r < 4; ++r) {
        // C/D layout (16x16x32 bf16): col = lane&15, row = (lane>>4)*4 + r
        const int row = blockIdx.x * 128 + wr + m * 16 + fq * 4 + r;
        const int col = blockIdx.y * 128 + wc + n * 16 + fr;
        const size_t idx = (size_t)row * Nd + col;
        if (EPI) {
          cb[idx] = fmaf(beta, acc[m][n][r], xres[(size_t)z * M * Nd + idx]);
        } else {
          cb[idx] = acc[m][n][r];
        }
      }
    }
  }
}

// ---------------------------------------------------------------------------
// Kernel 3: row softmax of (-S): attn = exp(min(S_row) - S) / sum.
// One wave per row (C=512 -> 8 fp32/lane), bf16 output.
// ---------------------------------------------------------------------------
__global__ __launch_bounds__(256) void k_softmax(
    const float* __restrict__ S, __hip_bfloat16* __restrict__ At) {
  const int row = blockIdx.x * 4 + (threadIdx.x >> 6);
  const int lane = threadIdx.x & 63;
  const float* sp = S + (size_t)row * Cx + lane * 8;
  float v[8];
  float4 f0 = *(const float4*)sp;
  float4 f1 = *(const float4*)(sp + 4);
  v[0] = f0.x; v[1] = f0.y; v[2] = f0.z; v[3] = f0.w;
  v[4] = f1.x; v[5] = f1.y; v[6] = f1.z; v[7] = f1.w;
  float mn = v[0];
#pragma unroll
  for (int j = 1; j < 8; ++j) mn = fminf(mn, v[j]);
#pragma unroll
  for (int off = 32; off; off >>= 1) mn = fminf(mn, __shfl_xor(mn, off));
  float w[8];
  float sum = 0.f;
#pragma unroll
  for (int j = 0; j < 8; ++j) {
    w[j] = __expf(mn - v[j]);  // <= 1, no overflow
    sum += w[j];
  }
#pragma unroll
  for (int off = 32; off; off >>= 1) sum += __shfl_xor(sum, off);
  const float inv = 1.f / sum;
  alignas(16) __hip_bfloat16 o[8];
#pragma unroll
  for (int j = 0; j < 8; ++j) o[j] = __float2bfloat16(w[j] * inv);
  *(uint4*)(At + (size_t)row * Cx + lane * 8) = *(const uint4*)o;
}

// ---------------------------------------------------------------------------
extern "C" void kernel_launch(void* const* d_in, const int* in_sizes, int n_in,
                              void* d_out, int out_size, void* d_ws,
                              size_t ws_size, hipStream_t stream) {
  const float* x = (const float*)d_in[0];
  const float* beta = (const float*)d_in[1];
  float* out = (float*)d_out;
  char* ws = (char*)d_ws;

  // ws layout: Xb (64 MiB) | XbT (64 MiB) | S fp32 (16 MiB) | attn bf16 (8 MiB)
  __hip_bfloat16* xb = (__hip_bfloat16*)ws;
  __hip_bfloat16* xbt = (__hip_bfloat16*)(ws + ((size_t)64 << 20));
  float* S = (float*)(ws + ((size_t)128 << 20));
  __hip_bfloat16* At = (__hip_bfloat16*)(ws + ((size_t)144 << 20));

  k_cast_transpose<<<dim3(Cx / 64, Nx / 64, Bx), 256, 0, stream>>>(x, xb, xbt);
  k_gemm_nt<false><<<dim3(Cx / 128, Cx / 128, Bx), 256, 0, stream>>>(
      xb, xb, S, nullptr, nullptr, Cx, Cx, Nx);
  k_softmax<<<(Bx * Cx) / 4, 256, 0, stream>>>(S, At);
  k_gemm_nt<true><<<dim3(Cx / 128, Nx / 128, Bx), 256, 0, stream>>>(
      At, xbt, out, x, beta, Cx, Nx, Cx);
}

// Round 2
// 222.889 us; speedup vs baseline: 1.1080x; 1.1080x over previous
//
#include <hip/hip_runtime.h>
#include <hip/hip_bf16.h>
#include <stdint.h>

#define DI __device__ __forceinline__

typedef __attribute__((ext_vector_type(8))) short bf16x8;
typedef __attribute__((ext_vector_type(4))) float f32x4;

static constexpr int Bx = 16, Cx = 512, Nx = 4096;

// async global->LDS, 16B per lane. LDS dst must be the WAVE-UNIFORM base;
// HW adds lane*16. Global src is per-lane.
DI void gload_lds16(const void* gsrc, void* ldst) {
  __builtin_amdgcn_global_load_lds(
      (const __attribute__((address_space(1))) uint32_t*)gsrc,
      (__attribute__((address_space(3))) uint32_t*)ldst, 16, 0, 0);
}

// ---------------------------------------------------------------------------
// Kernel 1: fp32 x -> bf16 Xb [B][C][N] and bf16 XbT [B][N][C]
// 64x64 tiles via LDS. grid (C/64, N/64, B), 256 threads.
// ---------------------------------------------------------------------------
__global__ __launch_bounds__(256) void k_cast_transpose(
    const float* __restrict__ x,
    __hip_bfloat16* __restrict__ xb,
    __hip_bfloat16* __restrict__ xbt) {
  __shared__ __hip_bfloat16 tile[64][65];
  const int b = blockIdx.z;
  const int c0 = blockIdx.x * 64;
  const int n0 = blockIdx.y * 64;
  const int t = threadIdx.x;
  const int r = t >> 2;          // 0..63
  const int q = (t & 3) * 16;    // 0,16,32,48

  const float* xp = x + ((size_t)b * Cx + (c0 + r)) * Nx + (n0 + q);
  alignas(16) __hip_bfloat16 v[16];
#pragma unroll
  for (int j = 0; j < 4; ++j) {
    float4 f = *(const float4*)(xp + j * 4);
    v[j * 4 + 0] = __float2bfloat16(f.x);
    v[j * 4 + 1] = __float2bfloat16(f.y);
    v[j * 4 + 2] = __float2bfloat16(f.z);
    v[j * 4 + 3] = __float2bfloat16(f.w);
  }
  __hip_bfloat16* xbp = xb + ((size_t)b * Cx + (c0 + r)) * Nx + (n0 + q);
  *(uint4*)xbp = *(const uint4*)&v[0];
  *(uint4*)(xbp + 8) = *(const uint4*)&v[8];
#pragma unroll
  for (int j = 0; j < 16; ++j) tile[r][q + j] = v[j];
  __syncthreads();
  alignas(16) __hip_bfloat16 o[16];
#pragma unroll
  for (int j = 0; j < 16; ++j) o[j] = tile[q + j][r];
  __hip_bfloat16* xtp = xbt + ((size_t)b * Nx + (n0 + r)) * Cx + (c0 + q);
  *(uint4*)xtp = *(const uint4*)&o[0];
  *(uint4*)(xtp + 8) = *(const uint4*)&o[8];
}

// ---------------------------------------------------------------------------
// NT bf16 GEMM: 128x128 tile, BK=32, 4 waves (2x2 of 64x64), double-buffered
// LDS (2-phase: stage next buf, compute cur, ONE __syncthreads per K-step),
// global_load_lds(16B) staging, v_mfma_f32_16x16x32_bf16, fp32 out.
// 1-D grid with XCD-chunked swizzle; logical (gx, gy, B*nsplit).
// Split-K: chunk kz covers K-range [kz*kLen, (kz+1)*kLen), output partial
// written to Co + (kz*Bx + b)*M*Nd.
// EPI: out = xres + beta*acc (residual add), else raw fp32 partial store.
// ---------------------------------------------------------------------------
template <bool EPI>
__global__ __launch_bounds__(256) void k_gemm_nt(
    const __hip_bfloat16* A, const __hip_bfloat16* Bt,
    float* __restrict__ Co, const float* __restrict__ xres,
    const float* __restrict__ betap, int M, int Nd, int K, int kLen,
    int nsplit, int gx, int gy) {
  // 2 buffers x (sA 8 KiB + sB 8 KiB) = 32 KiB
  __shared__ alignas(16) char lds[32768];

  // XCD-chunked bijective swizzle (grid divisible by 8)
  const int nblk = gridDim.x;
  int s = (blockIdx.x & 7) * (nblk >> 3) + (blockIdx.x >> 3);
  const int bxi = s % gx;
  s /= gx;
  const int byi = s % gy;
  s /= gy;
  const int b = s / nsplit;
  const int kz = s - b * nsplit;

  const int t = threadIdx.x;
  const int lane = t & 63;
  const int wave = t >> 6;
  const int wr = (wave >> 1) * 64;
  const int wc = (wave & 1) * 64;
  const int fr = lane & 15;
  const int fq = lane >> 4;

  const size_t aBase =
      (size_t)b * M * K + (size_t)(bxi * 128) * K + (size_t)kz * kLen;
  const size_t bBase =
      (size_t)b * Nd * K + (size_t)(byi * 128) * K + (size_t)kz * kLen;
  const int srow = t >> 2;
  const int skoff = (t & 3) * 8;

  f32x4 acc[4][4];
#pragma unroll
  for (int m = 0; m < 4; ++m)
#pragma unroll
    for (int n = 0; n < 4; ++n) acc[m][n] = {0.f, 0.f, 0.f, 0.f};

  auto STAGE = [&](int buf, int kt) {
    char* base = lds + buf * 16384 + (wave << 10);
    gload_lds16(A + aBase + (size_t)srow * K + kt + skoff, base);
    gload_lds16(A + aBase + (size_t)(srow + 64) * K + kt + skoff, base + 4096);
    gload_lds16(Bt + bBase + (size_t)srow * K + kt + skoff, base + 8192);
    gload_lds16(Bt + bBase + (size_t)(srow + 64) * K + kt + skoff,
                base + 8192 + 4096);
  };

  auto COMPUTE = [&](int buf) {
    const __hip_bfloat16* sA = (const __hip_bfloat16*)(lds + buf * 16384);
    const __hip_bfloat16* sB =
        (const __hip_bfloat16*)(lds + buf * 16384 + 8192);
    bf16x8 af[4], bfr[4];
#pragma unroll
    for (int m = 0; m < 4; ++m)
      af[m] = *(const bf16x8*)&sA[(wr + m * 16 + fr) * 32 + fq * 8];
#pragma unroll
    for (int n = 0; n < 4; ++n)
      bfr[n] = *(const bf16x8*)&sB[(wc + n * 16 + fr) * 32 + fq * 8];
#pragma unroll
    for (int m = 0; m < 4; ++m)
#pragma unroll
      for (int n = 0; n < 4; ++n)
        acc[m][n] = __builtin_amdgcn_mfma_f32_16x16x32_bf16(af[m], bfr[n],
                                                            acc[m][n], 0, 0, 0);
  };

  // kLen is always a multiple of 64 here (512..4096) -> unroll-2, static bufs
  STAGE(0, 0);
  __syncthreads();  // drain prologue (vmcnt(0) + barrier)
  for (int kt = 0; kt < kLen; kt += 64) {
    STAGE(1, kt + 32);  // always valid: kt+32 <= kLen-32
    COMPUTE(0);
    __syncthreads();  // drains STAGE(1) loads; all waves done reading buf0
    if (kt + 64 < kLen) STAGE(0, kt + 64);
    COMPUTE(1);
    __syncthreads();
  }

  const float beta = EPI ? betap[0] : 0.f;
  float* cb = Co + ((size_t)kz * Bx + b) * M * Nd;
#pragma unroll
  for (int m = 0; m < 4; ++m) {
#pragma unroll
    for (int n = 0; n < 4; ++n) {
#pragma unroll
      for (int r = 0; r < 4; ++r) {
        // C/D layout (16x16x32 bf16): col = lane&15, row = (lane>>4)*4 + r
        const int row = bxi * 128 + wr + m * 16 + fq * 4 + r;
        const int col = byi * 128 + wc + n * 16 + fr;
        const size_t idx = (size_t)row * Nd + col;
        if (EPI) {
          cb[idx] = fmaf(beta, acc[m][n][r], xres[(size_t)b * M * Nd + idx]);
        } else {
          cb[idx] = acc[m][n][r];
        }
      }
    }
  }
}

// ---------------------------------------------------------------------------
// Kernel 3: sum split-K partials, then row softmax of (-S):
// attn = exp(min(S_row) - S) / sum.  One wave per row, bf16 out.
// ---------------------------------------------------------------------------
__global__ __launch_bounds__(256) void k_softmax(
    const float* __restrict__ Sp, __hip_bfloat16* __restrict__ At, int nsplit,
    size_t pstride) {
  const int row = blockIdx.x * 4 + (threadIdx.x >> 6);
  const int lane = threadIdx.x & 63;
  float v[8] = {0.f, 0.f, 0.f, 0.f, 0.f, 0.f, 0.f, 0.f};
  for (int sp = 0; sp < nsplit; ++sp) {
    const float* p = Sp + sp * pstride + (size_t)row * Cx + lane * 8;
    float4 f0 = *(const float4*)p;
    float4 f1 = *(const float4*)(p + 4);
    v[0] += f0.x; v[1] += f0.y; v[2] += f0.z; v[3] += f0.w;
    v[4] += f1.x; v[5] += f1.y; v[6] += f1.z; v[7] += f1.w;
  }
  float mn = v[0];
#pragma unroll
  for (int j = 1; j < 8; ++j) mn = fminf(mn, v[j]);
#pragma unroll
  for (int off = 32; off; off >>= 1) mn = fminf(mn, __shfl_xor(mn, off));
  float w[8];
  float sum = 0.f;
#pragma unroll
  for (int j = 0; j < 8; ++j) {
    w[j] = __expf(mn - v[j]);  // <= 1, no overflow
    sum += w[j];
  }
#pragma unroll
  for (int off = 32; off; off >>= 1) sum += __shfl_xor(sum, off);
  const float inv = 1.f / sum;
  alignas(16) __hip_bfloat16 o[8];
#pragma unroll
  for (int j = 0; j < 8; ++j) o[j] = __float2bfloat16(w[j] * inv);
  *(uint4*)(At + (size_t)row * Cx + lane * 8) = *(const uint4*)o;
}

// ---------------------------------------------------------------------------
extern "C" void kernel_launch(void* const* d_in, const int* in_sizes, int n_in,
                              void* d_out, int out_size, void* d_ws,
                              size_t ws_size, hipStream_t stream) {
  const float* x = (const float*)d_in[0];
  const float* beta = (const float*)d_in[1];
  float* out = (float*)d_out;
  char* ws = (char*)d_ws;

  const size_t MB = (size_t)1 << 20;
  // ws layout: Xb 64 MiB | XbT 64 MiB | Sp nsplit*16 MiB | At 8 MiB
  // split-K factor chosen from available workspace (deterministic per run)
  int nsplit = 1;
  if (ws_size >= 200 * MB) nsplit = 4;
  else if (ws_size >= 168 * MB) nsplit = 2;

  __hip_bfloat16* xb = (__hip_bfloat16*)ws;
  __hip_bfloat16* xbt = (__hip_bfloat16*)(ws + 64 * MB);
  float* Sp = (float*)(ws + 128 * MB);
  __hip_bfloat16* At = (__hip_bfloat16*)(ws + (128 + 16 * (size_t)nsplit) * MB);
  const size_t pstride = (size_t)Bx * Cx * Cx;

  k_cast_transpose<<<dim3(Cx / 64, Nx / 64, Bx), 256, 0, stream>>>(x, xb, xbt);
  // GEMM1: S_partial[kz] = Xb * Xb^T over K-chunk kz. grid 16*16*nsplit blks.
  k_gemm_nt<false><<<(Cx / 128) * (Cx / 128) * Bx * nsplit, 256, 0, stream>>>(
      xb, xb, Sp, nullptr, nullptr, Cx, Cx, Nx, Nx / nsplit, nsplit, Cx / 128,
      Cx / 128);
  k_softmax<<<(Bx * Cx) / 4, 256, 0, stream>>>(Sp, At, nsplit, pstride);
  // GEMM2: out = beta*(attn * XbT^T) + x. grid 4*32*16 = 2048 blocks.
  k_gemm_nt<true><<<(Cx / 128) * (Nx / 128) * Bx, 256, 0, stream>>>(
      At, xbt, out, x, beta, Cx, Nx, Cx, Cx, 1, Cx / 128, Nx / 128);
}

// Round 3
// 214.660 us; speedup vs baseline: 1.1505x; 1.0383x over previous
//
#include <hip/hip_runtime.h>
#include <hip/hip_bf16.h>
#include <stdint.h>

#define DI __device__ __forceinline__

typedef __attribute__((ext_vector_type(8))) short bf16x8;
typedef __attribute__((ext_vector_type(4))) float f32x4;

static constexpr int Bx = 16, Cx = 512, Nx = 4096;

// async global->LDS, 16B per lane. LDS dst must be the WAVE-UNIFORM base;
// HW adds lane*16. Global src is per-lane.
DI void gload_lds16(const void* gsrc, void* ldst) {
  __builtin_amdgcn_global_load_lds(
      (const __attribute__((address_space(1))) uint32_t*)gsrc,
      (__attribute__((address_space(3))) uint32_t*)ldst, 16, 0, 0);
}

// ---------------------------------------------------------------------------
// Kernel 1: fp32 x -> bf16 Xb [B][C][N] and bf16 XbT [B][N][C]
// 64x64 tiles via LDS. grid (C/64, N/64, B), 256 threads.
// ---------------------------------------------------------------------------
__global__ __launch_bounds__(256) void k_cast_transpose(
    const float* __restrict__ x,
    __hip_bfloat16* __restrict__ xb,
    __hip_bfloat16* __restrict__ xbt) {
  __shared__ __hip_bfloat16 tile[64][65];
  const int b = blockIdx.z;
  const int c0 = blockIdx.x * 64;
  const int n0 = blockIdx.y * 64;
  const int t = threadIdx.x;
  const int r = t >> 2;          // 0..63
  const int q = (t & 3) * 16;    // 0,16,32,48

  const float* xp = x + ((size_t)b * Cx + (c0 + r)) * Nx + (n0 + q);
  alignas(16) __hip_bfloat16 v[16];
#pragma unroll
  for (int j = 0; j < 4; ++j) {
    float4 f = *(const float4*)(xp + j * 4);
    v[j * 4 + 0] = __float2bfloat16(f.x);
    v[j * 4 + 1] = __float2bfloat16(f.y);
    v[j * 4 + 2] = __float2bfloat16(f.z);
    v[j * 4 + 3] = __float2bfloat16(f.w);
  }
  __hip_bfloat16* xbp = xb + ((size_t)b * Cx + (c0 + r)) * Nx + (n0 + q);
  *(uint4*)xbp = *(const uint4*)&v[0];
  *(uint4*)(xbp + 8) = *(const uint4*)&v[8];
#pragma unroll
  for (int j = 0; j < 16; ++j) tile[r][q + j] = v[j];
  __syncthreads();
  alignas(16) __hip_bfloat16 o[16];
#pragma unroll
  for (int j = 0; j < 16; ++j) o[j] = tile[q + j][r];
  __hip_bfloat16* xtp = xbt + ((size_t)b * Nx + (n0 + r)) * Cx + (c0 + q);
  *(uint4*)xtp = *(const uint4*)&o[0];
  *(uint4*)(xtp + 8) = *(const uint4*)&o[8];
}

// ---------------------------------------------------------------------------
// NT bf16 GEMM: 128x128 tile, BK=32, 4 waves (2x2 of 64x64).
// T4 counted-vmcnt double-buffer: prefetch next tile's 4 global_load_lds,
// raw s_barrier + s_waitcnt vmcnt(4) -- prefetch stays in flight across
// barriers (never vmcnt(0) in the main loop).
// T2 LDS swizzle: k-block slot' = slot ^ ((row>>1)&3), applied to the
// global SOURCE (linear global_load_lds dst) and to the ds_read offset
// (same involution both sides).
// Split-K: chunk kz covers [kz*kLen, (kz+1)*kLen); partial -> Co + (kz*Bx+b)*M*Nd.
// EPI: out = xres + beta*acc.
// ---------------------------------------------------------------------------
template <bool EPI>
__global__ __launch_bounds__(256) void k_gemm_nt(
    const __hip_bfloat16* A, const __hip_bfloat16* Bt,
    float* __restrict__ Co, const float* __restrict__ xres,
    const float* __restrict__ betap, int M, int Nd, int K, int kLen,
    int nsplit, int gx, int gy) {
  __shared__ alignas(16) char lds[32768];  // 2 bufs x (sA 8K + sB 8K)

  // XCD-chunked bijective swizzle (grid divisible by 8)
  const int nblk = gridDim.x;
  int s = (blockIdx.x & 7) * (nblk >> 3) + (blockIdx.x >> 3);
  const int bxi = s % gx;
  s /= gx;
  const int byi = s % gy;
  s /= gy;
  const int b = s / nsplit;
  const int kz = s - b * nsplit;

  const int t = threadIdx.x;
  const int lane = t & 63;
  const int wave = t >> 6;
  const int wr = (wave >> 1) * 64;
  const int wc = (wave & 1) * 64;
  const int fr = lane & 15;
  const int fq = lane >> 4;
  const int perm = (fr >> 1) & 3;  // read-side swizzle (row>>1)&3, row==fr mod16

  const size_t aBase =
      (size_t)b * M * K + (size_t)(bxi * 128) * K + (size_t)kz * kLen;
  const size_t bBase =
      (size_t)b * Nd * K + (size_t)(byi * 128) * K + (size_t)kz * kLen;
  const int srow = t >> 2;
  // source k-offset pre-swizzled: slot (t&3) receives global block (t&3)^sw
  const int skoff = (((t & 3) ^ ((t >> 3) & 3)) * 8);

  f32x4 acc[4][4];
#pragma unroll
  for (int m = 0; m < 4; ++m)
#pragma unroll
    for (int n = 0; n < 4; ++n) acc[m][n] = {0.f, 0.f, 0.f, 0.f};

  auto STAGE = [&](int buf, int kt) {
    char* base = lds + buf * 16384 + (wave << 10);
    gload_lds16(A + aBase + (size_t)srow * K + kt + skoff, base);
    gload_lds16(A + aBase + (size_t)(srow + 64) * K + kt + skoff, base + 4096);
    gload_lds16(Bt + bBase + (size_t)srow * K + kt + skoff, base + 8192);
    gload_lds16(Bt + bBase + (size_t)(srow + 64) * K + kt + skoff,
                base + 8192 + 4096);
  };

  auto COMPUTE = [&](int buf) {
    const __hip_bfloat16* sA = (const __hip_bfloat16*)(lds + buf * 16384);
    const __hip_bfloat16* sB =
        (const __hip_bfloat16*)(lds + buf * 16384 + 8192);
    bf16x8 af[4], bfr[4];
#pragma unroll
    for (int m = 0; m < 4; ++m)
      af[m] = *(const bf16x8*)&sA[(wr + m * 16 + fr) * 32 + ((fq ^ perm) * 8)];
#pragma unroll
    for (int n = 0; n < 4; ++n)
      bfr[n] = *(const bf16x8*)&sB[(wc + n * 16 + fr) * 32 + ((fq ^ perm) * 8)];
#pragma unroll
    for (int m = 0; m < 4; ++m)
#pragma unroll
      for (int n = 0; n < 4; ++n)
        acc[m][n] = __builtin_amdgcn_mfma_f32_16x16x32_bf16(af[m], bfr[n],
                                                            acc[m][n], 0, 0, 0);
  };

  const int nt = kLen >> 5;  // BK=32 steps
  STAGE(0, 0);
  for (int it = 0; it < nt - 1; ++it) {
    STAGE((it + 1) & 1, (it + 1) << 5);  // 4 more loads (8 in flight)
    // wait only the 4 oldest (tile it); prefetch stays in flight
    asm volatile("s_waitcnt vmcnt(4)" ::: "memory");
    __builtin_amdgcn_s_barrier();
    __builtin_amdgcn_sched_barrier(0);
    COMPUTE(it & 1);
    __builtin_amdgcn_s_barrier();  // all waves done reading buf before restage
    __builtin_amdgcn_sched_barrier(0);
  }
  asm volatile("s_waitcnt vmcnt(0)" ::: "memory");
  __builtin_amdgcn_s_barrier();
  __builtin_amdgcn_sched_barrier(0);
  COMPUTE((nt - 1) & 1);

  const float beta = EPI ? betap[0] : 0.f;
  float* cb = Co + ((size_t)kz * Bx + b) * M * Nd;
#pragma unroll
  for (int m = 0; m < 4; ++m) {
#pragma unroll
    for (int n = 0; n < 4; ++n) {
#pragma unroll
      for (int r = 0; r < 4; ++r) {
        // C/D layout (16x16x32 bf16): col = lane&15, row = (lane>>4)*4 + r
        const int row = bxi * 128 + wr + m * 16 + fq * 4 + r;
        const int col = byi * 128 + wc + n * 16 + fr;
        const size_t idx = (size_t)row * Nd + col;
        if (EPI) {
          cb[idx] = fmaf(beta, acc[m][n][r], xres[(size_t)b * M * Nd + idx]);
        } else {
          cb[idx] = acc[m][n][r];
        }
      }
    }
  }
}

// ---------------------------------------------------------------------------
// Kernel 3: sum split-K partials, then row softmax of (-S):
// attn = exp(min(S_row) - S) / sum.  One wave per row, bf16 out.
// ---------------------------------------------------------------------------
__global__ __launch_bounds__(256) void k_softmax(
    const float* __restrict__ Sp, __hip_bfloat16* __restrict__ At, int nsplit,
    size_t pstride) {
  const int row = blockIdx.x * 4 + (threadIdx.x >> 6);
  const int lane = threadIdx.x & 63;
  float v[8] = {0.f, 0.f, 0.f, 0.f, 0.f, 0.f, 0.f, 0.f};
  for (int sp = 0; sp < nsplit; ++sp) {
    const float* p = Sp + sp * pstride + (size_t)row * Cx + lane * 8;
    float4 f0 = *(const float4*)p;
    float4 f1 = *(const float4*)(p + 4);
    v[0] += f0.x; v[1] += f0.y; v[2] += f0.z; v[3] += f0.w;
    v[4] += f1.x; v[5] += f1.y; v[6] += f1.z; v[7] += f1.w;
  }
  float mn = v[0];
#pragma unroll
  for (int j = 1; j < 8; ++j) mn = fminf(mn, v[j]);
#pragma unroll
  for (int off = 32; off; off >>= 1) mn = fminf(mn, __shfl_xor(mn, off));
  float w[8];
  float sum = 0.f;
#pragma unroll
  for (int j = 0; j < 8; ++j) {
    w[j] = __expf(mn - v[j]);  // <= 1, no overflow
    sum += w[j];
  }
#pragma unroll
  for (int off = 32; off; off >>= 1) sum += __shfl_xor(sum, off);
  const float inv = 1.f / sum;
  alignas(16) __hip_bfloat16 o[8];
#pragma unroll
  for (int j = 0; j < 8; ++j) o[j] = __float2bfloat16(w[j] * inv);
  *(uint4*)(At + (size_t)row * Cx + lane * 8) = *(const uint4*)o;
}

// ---------------------------------------------------------------------------
extern "C" void kernel_launch(void* const* d_in, const int* in_sizes, int n_in,
                              void* d_out, int out_size, void* d_ws,
                              size_t ws_size, hipStream_t stream) {
  const float* x = (const float*)d_in[0];
  const float* beta = (const float*)d_in[1];
  float* out = (float*)d_out;
  char* ws = (char*)d_ws;

  const size_t MB = (size_t)1 << 20;
  // ws layout: Xb 64 MiB | XbT 64 MiB | At 8 MiB  (fits ws >= 152 MiB)
  // Split-K partials live in d_out (134 MiB scratch until GEMM2 overwrites it).
  const int nsplit = 4;  // Sp = 4 * 16.78 MB = 67 MB <= out buffer
  __hip_bfloat16* xb = (__hip_bfloat16*)ws;
  __hip_bfloat16* xbt = (__hip_bfloat16*)(ws + 64 * MB);
  __hip_bfloat16* At = (__hip_bfloat16*)(ws + 128 * MB);
  float* Sp = out;  // scratch: overwritten by GEMM2 afterwards
  const size_t pstride = (size_t)Bx * Cx * Cx;

  k_cast_transpose<<<dim3(Cx / 64, Nx / 64, Bx), 256, 0, stream>>>(x, xb, xbt);
  // GEMM1: S_partial[kz] = Xb * Xb^T over K-chunk kz. grid 4*4*16*4 = 1024.
  k_gemm_nt<false><<<(Cx / 128) * (Cx / 128) * Bx * nsplit, 256, 0, stream>>>(
      xb, xb, Sp, nullptr, nullptr, Cx, Cx, Nx, Nx / nsplit, nsplit, Cx / 128,
      Cx / 128);
  k_softmax<<<(Bx * Cx) / 4, 256, 0, stream>>>(Sp, At, nsplit, pstride);
  // GEMM2: out = beta*(attn * XbT^T) + x. grid 4*32*16 = 2048 blocks.
  k_gemm_nt<true><<<(Cx / 128) * (Nx / 128) * Bx, 256, 0, stream>>>(
      At, xbt, out, x, beta, Cx, Nx, Cx, Cx, 1, Cx / 128, Nx / 128);
}

// Round 4
// 211.543 us; speedup vs baseline: 1.1674x; 1.0147x over previous
//
#include <hip/hip_runtime.h>
#include <hip/hip_bf16.h>
#include <stdint.h>

#define DI __device__ __forceinline__

typedef __attribute__((ext_vector_type(8))) short bf16x8;
typedef __attribute__((ext_vector_type(4))) float f32x4;

static constexpr int Bx = 16, Cx = 512, Nx = 4096;

// async global->LDS, 16B per lane. LDS dst must be the WAVE-UNIFORM base;
// HW adds lane*16. Global src is per-lane.
DI void gload_lds16(const void* gsrc, void* ldst) {
  __builtin_amdgcn_global_load_lds(
      (const __attribute__((address_space(1))) uint32_t*)gsrc,
      (__attribute__((address_space(3))) uint32_t*)ldst, 16, 0, 0);
}

// ---------------------------------------------------------------------------
// Kernel 1: fp32 x -> bf16 Xb [B][C][N] and bf16 XbT [B][N][C]
// ---------------------------------------------------------------------------
__global__ __launch_bounds__(256) void k_cast_transpose(
    const float* __restrict__ x,
    __hip_bfloat16* __restrict__ xb,
    __hip_bfloat16* __restrict__ xbt) {
  __shared__ __hip_bfloat16 tile[64][65];
  const int b = blockIdx.z;
  const int c0 = blockIdx.x * 64;
  const int n0 = blockIdx.y * 64;
  const int t = threadIdx.x;
  const int r = t >> 2;          // 0..63
  const int q = (t & 3) * 16;    // 0,16,32,48

  const float* xp = x + ((size_t)b * Cx + (c0 + r)) * Nx + (n0 + q);
  alignas(16) __hip_bfloat16 v[16];
#pragma unroll
  for (int j = 0; j < 4; ++j) {
    float4 f = *(const float4*)(xp + j * 4);
    v[j * 4 + 0] = __float2bfloat16(f.x);
    v[j * 4 + 1] = __float2bfloat16(f.y);
    v[j * 4 + 2] = __float2bfloat16(f.z);
    v[j * 4 + 3] = __float2bfloat16(f.w);
  }
  __hip_bfloat16* xbp = xb + ((size_t)b * Cx + (c0 + r)) * Nx + (n0 + q);
  *(uint4*)xbp = *(const uint4*)&v[0];
  *(uint4*)(xbp + 8) = *(const uint4*)&v[8];
#pragma unroll
  for (int j = 0; j < 16; ++j) tile[r][q + j] = v[j];
  __syncthreads();
  alignas(16) __hip_bfloat16 o[16];
#pragma unroll
  for (int j = 0; j < 16; ++j) o[j] = tile[q + j][r];
  __hip_bfloat16* xtp = xbt + ((size_t)b * Nx + (n0 + r)) * Cx + (c0 + q);
  *(uint4*)xtp = *(const uint4*)&o[0];
  *(uint4*)(xtp + 8) = *(const uint4*)&o[8];
}

// ---------------------------------------------------------------------------
// NT bf16 GEMM: 128x128 tile, BK=32, 4 waves (2x2 of 64x64).
// TRIPLE-buffered LDS, ONE barrier + counted vmcnt per K-step:
//   step it: vmcnt(4) [tile it landed] -> s_barrier [all waves: tile it
//   visible AND compute(it-1) done] -> STAGE(it+2) [overwrites buffer last
//   read at it-1: safe] -> COMPUTE(it).
// Latency budget = 2 full steps (tile it+2 issued at it, waited at it+2).
// T2 LDS swizzle both-sides (pre-swizzled global source, XOR'd ds_read).
// EPI: xres loads issued before the FINAL compute (latency hidden under
// 256 MFMAs), epilogue is stores-only.
// ---------------------------------------------------------------------------
template <bool EPI>
__global__ __launch_bounds__(256) void k_gemm_nt(
    const __hip_bfloat16* A, const __hip_bfloat16* Bt,
    float* __restrict__ Co, const float* __restrict__ xres,
    const float* __restrict__ betap, int M, int Nd, int K, int kLen,
    int nsplit, int gx, int gy) {
  __shared__ alignas(16) char lds[49152];  // 3 bufs x (sA 8K + sB 8K)

  // XCD-chunked bijective swizzle (grid divisible by 8)
  const int nblk = gridDim.x;
  int s = (blockIdx.x & 7) * (nblk >> 3) + (blockIdx.x >> 3);
  const int bxi = s % gx;
  s /= gx;
  const int byi = s % gy;
  s /= gy;
  const int b = s / nsplit;
  const int kz = s - b * nsplit;

  const int t = threadIdx.x;
  const int lane = t & 63;
  const int wave = t >> 6;
  const int wr = (wave >> 1) * 64;
  const int wc = (wave & 1) * 64;
  const int fr = lane & 15;
  const int fq = lane >> 4;
  const int perm = (fr >> 1) & 3;  // read-side swizzle

  const size_t aBase =
      (size_t)b * M * K + (size_t)(bxi * 128) * K + (size_t)kz * kLen;
  const size_t bBase =
      (size_t)b * Nd * K + (size_t)(byi * 128) * K + (size_t)kz * kLen;
  const int srow = t >> 2;
  // source k-offset pre-swizzled (matches read-side XOR)
  const int skoff = (((t & 3) ^ ((t >> 3) & 3)) * 8);

  f32x4 acc[4][4];
#pragma unroll
  for (int m = 0; m < 4; ++m)
#pragma unroll
    for (int n = 0; n < 4; ++n) acc[m][n] = {0.f, 0.f, 0.f, 0.f};

  auto STAGE = [&](char* bufbase, int kt) {
    char* base = bufbase + (wave << 10);
    gload_lds16(A + aBase + (size_t)srow * K + kt + skoff, base);
    gload_lds16(A + aBase + (size_t)(srow + 64) * K + kt + skoff, base + 4096);
    gload_lds16(Bt + bBase + (size_t)srow * K + kt + skoff, base + 8192);
    gload_lds16(Bt + bBase + (size_t)(srow + 64) * K + kt + skoff,
                base + 12288);
  };

  auto COMPUTE = [&](const char* p) {
    const __hip_bfloat16* sA = (const __hip_bfloat16*)p;
    const __hip_bfloat16* sB = (const __hip_bfloat16*)(p + 8192);
    bf16x8 af[4], bfr[4];
#pragma unroll
    for (int m = 0; m < 4; ++m)
      af[m] = *(const bf16x8*)&sA[(wr + m * 16 + fr) * 32 + ((fq ^ perm) * 8)];
#pragma unroll
    for (int n = 0; n < 4; ++n)
      bfr[n] = *(const bf16x8*)&sB[(wc + n * 16 + fr) * 32 + ((fq ^ perm) * 8)];
#pragma unroll
    for (int m = 0; m < 4; ++m)
#pragma unroll
      for (int n = 0; n < 4; ++n)
        acc[m][n] = __builtin_amdgcn_mfma_f32_16x16x32_bf16(af[m], bfr[n],
                                                            acc[m][n], 0, 0, 0);
  };

  const int nt = kLen >> 5;  // BK=32 steps (nt >= 8 for all our shapes)
  char* pb0 = lds;
  char* pb1 = lds + 16384;
  char* pb2 = lds + 32768;
  STAGE(pb0, 0);
  STAGE(pb1, 32);
  for (int it = 0; it < nt - 1; ++it) {
    asm volatile("s_waitcnt vmcnt(4)" ::: "memory");
    __builtin_amdgcn_s_barrier();
    __builtin_amdgcn_sched_barrier(0);
    if (it + 2 < nt) STAGE(pb2, (it + 2) << 5);
    COMPUTE(pb0);
    char* tmp = pb0; pb0 = pb1; pb1 = pb2; pb2 = tmp;
  }
  asm volatile("s_waitcnt vmcnt(0)" ::: "memory");
  __builtin_amdgcn_s_barrier();
  __builtin_amdgcn_sched_barrier(0);

  // EPI: issue residual loads now; latency hides under the final COMPUTE.
  float xr[4][4][4];
  if (EPI) {
#pragma unroll
    for (int m = 0; m < 4; ++m)
#pragma unroll
      for (int n = 0; n < 4; ++n)
#pragma unroll
        for (int r = 0; r < 4; ++r)
          xr[m][n][r] =
              xres[(size_t)b * M * Nd +
                   (size_t)(bxi * 128 + wr + m * 16 + fq * 4 + r) * Nd +
                   (byi * 128 + wc + n * 16 + fr)];
  }
  COMPUTE(pb0);

  const float beta = EPI ? betap[0] : 0.f;
  float* cb = Co + ((size_t)kz * Bx + b) * M * Nd;
#pragma unroll
  for (int m = 0; m < 4; ++m) {
#pragma unroll
    for (int n = 0; n < 4; ++n) {
#pragma unroll
      for (int r = 0; r < 4; ++r) {
        // C/D layout (16x16x32 bf16): col = lane&15, row = (lane>>4)*4 + r
        const int row = bxi * 128 + wr + m * 16 + fq * 4 + r;
        const int col = byi * 128 + wc + n * 16 + fr;
        const size_t idx = (size_t)row * Nd + col;
        if (EPI) {
          cb[idx] = fmaf(beta, acc[m][n][r], xr[m][n][r]);
        } else {
          cb[idx] = acc[m][n][r];
        }
      }
    }
  }
}

// ---------------------------------------------------------------------------
// Kernel 3: sum split-K partials, then row softmax of (-S):
// attn = exp(min(S_row) - S) / sum.  One wave per row, bf16 out.
// ---------------------------------------------------------------------------
__global__ __launch_bounds__(256) void k_softmax(
    const float* __restrict__ Sp, __hip_bfloat16* __restrict__ At, int nsplit,
    size_t pstride) {
  const int row = blockIdx.x * 4 + (threadIdx.x >> 6);
  const int lane = threadIdx.x & 63;
  float v[8] = {0.f, 0.f, 0.f, 0.f, 0.f, 0.f, 0.f, 0.f};
  for (int sp = 0; sp < nsplit; ++sp) {
    const float* p = Sp + sp * pstride + (size_t)row * Cx + lane * 8;
    float4 f0 = *(const float4*)p;
    float4 f1 = *(const float4*)(p + 4);
    v[0] += f0.x; v[1] += f0.y; v[2] += f0.z; v[3] += f0.w;
    v[4] += f1.x; v[5] += f1.y; v[6] += f1.z; v[7] += f1.w;
  }
  float mn = v[0];
#pragma unroll
  for (int j = 1; j < 8; ++j) mn = fminf(mn, v[j]);
#pragma unroll
  for (int off = 32; off; off >>= 1) mn = fminf(mn, __shfl_xor(mn, off));
  float w[8];
  float sum = 0.f;
#pragma unroll
  for (int j = 0; j < 8; ++j) {
    w[j] = __expf(mn - v[j]);  // <= 1, no overflow
    sum += w[j];
  }
#pragma unroll
  for (int off = 32; off; off >>= 1) sum += __shfl_xor(sum, off);
  const float inv = 1.f / sum;
  alignas(16) __hip_bfloat16 o[8];
#pragma unroll
  for (int j = 0; j < 8; ++j) o[j] = __float2bfloat16(w[j] * inv);
  *(uint4*)(At + (size_t)row * Cx + lane * 8) = *(const uint4*)o;
}

// ---------------------------------------------------------------------------
extern "C" void kernel_launch(void* const* d_in, const int* in_sizes, int n_in,
                              void* d_out, int out_size, void* d_ws,
                              size_t ws_size, hipStream_t stream) {
  const float* x = (const float*)d_in[0];
  const float* beta = (const float*)d_in[1];
  float* out = (float*)d_out;
  char* ws = (char*)d_ws;

  const size_t MB = (size_t)1 << 20;
  // ws layout: Xb 64 MiB | XbT 64 MiB | At 8 MiB.
  // Split-K partials live in d_out (134 MiB scratch until GEMM2 overwrites).
  const int nsplit = 4;
  __hip_bfloat16* xb = (__hip_bfloat16*)ws;
  __hip_bfloat16* xbt = (__hip_bfloat16*)(ws + 64 * MB);
  __hip_bfloat16* At = (__hip_bfloat16*)(ws + 128 * MB);
  float* Sp = out;
  const size_t pstride = (size_t)Bx * Cx * Cx;

  k_cast_transpose<<<dim3(Cx / 64, Nx / 64, Bx), 256, 0, stream>>>(x, xb, xbt);
  // GEMM1: S_partial[kz] = Xb * Xb^T over K-chunk kz. grid 1024 blocks.
  k_gemm_nt<false><<<(Cx / 128) * (Cx / 128) * Bx * nsplit, 256, 0, stream>>>(
      xb, xb, Sp, nullptr, nullptr, Cx, Cx, Nx, Nx / nsplit, nsplit, Cx / 128,
      Cx / 128);
  k_softmax<<<(Bx * Cx) / 4, 256, 0, stream>>>(Sp, At, nsplit, pstride);
  // GEMM2: out = beta*(attn * XbT^T) + x. grid 2048 blocks.
  k_gemm_nt<true><<<(Cx / 128) * (Nx / 128) * Bx, 256, 0, stream>>>(
      At, xbt, out, x, beta, Cx, Nx, Cx, Cx, 1, Cx / 128, Nx / 128);
}

// Round 5
// 207.877 us; speedup vs baseline: 1.1880x; 1.0176x over previous
//
#include <hip/hip_runtime.h>
#include <hip/hip_bf16.h>
#include <stdint.h>

#define DI __device__ __forceinline__

typedef __attribute__((ext_vector_type(8))) short bf16x8;
typedef __attribute__((ext_vector_type(4))) float f32x4;

static constexpr int Bx = 16, Cx = 512, Nx = 4096;

// async global->LDS, 16B per lane. LDS dst must be the WAVE-UNIFORM base;
// HW adds lane*16. Global src is per-lane.
DI void gload_lds16(const void* gsrc, void* ldst) {
  __builtin_amdgcn_global_load_lds(
      (const __attribute__((address_space(1))) uint32_t*)gsrc,
      (__attribute__((address_space(3))) uint32_t*)ldst, 16, 0, 0);
}

// ---------------------------------------------------------------------------
// Kernel 1: fp32 x -> bf16 Xb [B][C][N] and bf16 XbT [B][N][C]
// ---------------------------------------------------------------------------
__global__ __launch_bounds__(256) void k_cast_transpose(
    const float* __restrict__ x,
    __hip_bfloat16* __restrict__ xb,
    __hip_bfloat16* __restrict__ xbt) {
  __shared__ __hip_bfloat16 tile[64][65];
  const int b = blockIdx.z;
  const int c0 = blockIdx.x * 64;
  const int n0 = blockIdx.y * 64;
  const int t = threadIdx.x;
  const int r = t >> 2;          // 0..63
  const int q = (t & 3) * 16;    // 0,16,32,48

  const float* xp = x + ((size_t)b * Cx + (c0 + r)) * Nx + (n0 + q);
  alignas(16) __hip_bfloat16 v[16];
#pragma unroll
  for (int j = 0; j < 4; ++j) {
    float4 f = *(const float4*)(xp + j * 4);
    v[j * 4 + 0] = __float2bfloat16(f.x);
    v[j * 4 + 1] = __float2bfloat16(f.y);
    v[j * 4 + 2] = __float2bfloat16(f.z);
    v[j * 4 + 3] = __float2bfloat16(f.w);
  }
  __hip_bfloat16* xbp = xb + ((size_t)b * Cx + (c0 + r)) * Nx + (n0 + q);
  *(uint4*)xbp = *(const uint4*)&v[0];
  *(uint4*)(xbp + 8) = *(const uint4*)&v[8];
#pragma unroll
  for (int j = 0; j < 16; ++j) tile[r][q + j] = v[j];
  __syncthreads();
  alignas(16) __hip_bfloat16 o[16];
#pragma unroll
  for (int j = 0; j < 16; ++j) o[j] = tile[q + j][r];
  __hip_bfloat16* xtp = xbt + ((size_t)b * Nx + (n0 + r)) * Cx + (c0 + q);
  *(uint4*)xtp = *(const uint4*)&o[0];
  *(uint4*)(xtp + 8) = *(const uint4*)&o[8];
}

// ---------------------------------------------------------------------------
// NT bf16 GEMM: 128x128 tile, BK=32, 4 waves (2x2 of 64x64).
// Triple-buffered LDS, ONE barrier + counted vmcnt(4) per K-step.
// T2 LDS swizzle both-sides. T1 XCD-chunked grid swizzle.
// NEW: LDS-staged coalesced epilogue — acc is round-tripped through LDS in
// two 64-row chunks; global loads/stores are flat float4 (1KB/wave/instr,
// each wave = 2 full 512B rows) instead of 64B scattered segments.
// EPI: out = xres + beta*acc (xres loaded in the same coalesced pattern).
// ---------------------------------------------------------------------------
template <bool EPI>
__global__ __launch_bounds__(256) void k_gemm_nt(
    const __hip_bfloat16* A, const __hip_bfloat16* Bt,
    float* __restrict__ Co, const float* __restrict__ xres,
    const float* __restrict__ betap, int M, int Nd, int K, int kLen,
    int nsplit, int gx, int gy) {
  __shared__ alignas(16) char lds[49152];  // 3 bufs x (sA 8K + sB 8K)

  // XCD-chunked bijective swizzle (grid divisible by 8)
  const int nblk = gridDim.x;
  int s = (blockIdx.x & 7) * (nblk >> 3) + (blockIdx.x >> 3);
  const int bxi = s % gx;
  s /= gx;
  const int byi = s % gy;
  s /= gy;
  const int b = s / nsplit;
  const int kz = s - b * nsplit;

  const int t = threadIdx.x;
  const int lane = t & 63;
  const int wave = t >> 6;
  const int wr = (wave >> 1) * 64;
  const int wc = (wave & 1) * 64;
  const int fr = lane & 15;
  const int fq = lane >> 4;
  const int perm = (fr >> 1) & 3;  // read-side swizzle

  const size_t aBase =
      (size_t)b * M * K + (size_t)(bxi * 128) * K + (size_t)kz * kLen;
  const size_t bBase =
      (size_t)b * Nd * K + (size_t)(byi * 128) * K + (size_t)kz * kLen;
  const int srow = t >> 2;
  // source k-offset pre-swizzled (matches read-side XOR)
  const int skoff = (((t & 3) ^ ((t >> 3) & 3)) * 8);

  f32x4 acc[4][4];
#pragma unroll
  for (int m = 0; m < 4; ++m)
#pragma unroll
    for (int n = 0; n < 4; ++n) acc[m][n] = {0.f, 0.f, 0.f, 0.f};

  auto STAGE = [&](char* bufbase, int kt) {
    char* base = bufbase + (wave << 10);
    gload_lds16(A + aBase + (size_t)srow * K + kt + skoff, base);
    gload_lds16(A + aBase + (size_t)(srow + 64) * K + kt + skoff, base + 4096);
    gload_lds16(Bt + bBase + (size_t)srow * K + kt + skoff, base + 8192);
    gload_lds16(Bt + bBase + (size_t)(srow + 64) * K + kt + skoff,
                base + 12288);
  };

  auto COMPUTE = [&](const char* p) {
    const __hip_bfloat16* sA = (const __hip_bfloat16*)p;
    const __hip_bfloat16* sB = (const __hip_bfloat16*)(p + 8192);
    bf16x8 af[4], bfr[4];
#pragma unroll
    for (int m = 0; m < 4; ++m)
      af[m] = *(const bf16x8*)&sA[(wr + m * 16 + fr) * 32 + ((fq ^ perm) * 8)];
#pragma unroll
    for (int n = 0; n < 4; ++n)
      bfr[n] = *(const bf16x8*)&sB[(wc + n * 16 + fr) * 32 + ((fq ^ perm) * 8)];
#pragma unroll
    for (int m = 0; m < 4; ++m)
#pragma unroll
      for (int n = 0; n < 4; ++n)
        acc[m][n] = __builtin_amdgcn_mfma_f32_16x16x32_bf16(af[m], bfr[n],
                                                            acc[m][n], 0, 0, 0);
  };

  const int nt = kLen >> 5;  // BK=32 steps
  char* pb0 = lds;
  char* pb1 = lds + 16384;
  char* pb2 = lds + 32768;
  STAGE(pb0, 0);
  STAGE(pb1, 32);
  for (int it = 0; it < nt - 1; ++it) {
    asm volatile("s_waitcnt vmcnt(4)" ::: "memory");
    __builtin_amdgcn_s_barrier();
    __builtin_amdgcn_sched_barrier(0);
    if (it + 2 < nt) STAGE(pb2, (it + 2) << 5);
    COMPUTE(pb0);
    char* tmp = pb0; pb0 = pb1; pb1 = pb2; pb2 = tmp;
  }
  asm volatile("s_waitcnt vmcnt(0)" ::: "memory");
  __builtin_amdgcn_s_barrier();
  __builtin_amdgcn_sched_barrier(0);
  COMPUTE(pb0);

  // ---- LDS-staged coalesced epilogue ----
  __syncthreads();  // all waves done reading K-loop LDS
  const float beta = EPI ? betap[0] : 0.f;
  float* lds_f = (float*)lds;  // 64 rows x 128 cols fp32 = 32 KiB
  float* cb = Co + ((size_t)kz * Bx + b) * M * Nd;
  const float* xb = EPI ? (xres + (size_t)b * M * Nd) : nullptr;

#pragma unroll
  for (int h = 0; h < 2; ++h) {
    if (wr == h * 64) {
#pragma unroll
      for (int m = 0; m < 4; ++m)
#pragma unroll
        for (int n = 0; n < 4; ++n)
#pragma unroll
          for (int r = 0; r < 4; ++r)
            lds_f[(m * 16 + fq * 4 + r) * 128 + (wc + n * 16 + fr)] =
                acc[m][n][r];
    }
    __syncthreads();
#pragma unroll
    for (int j = 0; j < 8; ++j) {
      const int f4 = j * 256 + t;       // flat float4 index in 64x128 chunk
      const int rloc = f4 >> 5;         // 32 float4 per row
      const int c0 = (f4 & 31) << 2;    // col in floats
      const int grow = bxi * 128 + h * 64 + rloc;
      const int gcol = byi * 128 + c0;
      f32x4 v = *(const f32x4*)&lds_f[rloc * 128 + c0];
      const size_t gidx = (size_t)grow * Nd + gcol;
      if (EPI) {
        f32x4 xv = *(const f32x4*)&xb[gidx];
#pragma unroll
        for (int e = 0; e < 4; ++e) v[e] = fmaf(beta, v[e], xv[e]);
      }
      *(f32x4*)&cb[gidx] = v;
    }
    __syncthreads();
  }
}

// ---------------------------------------------------------------------------
// Kernel 3: sum split-K partials, then row softmax of (-S):
// attn = exp(min(S_row) - S) / sum.  One wave per row, bf16 out.
// ---------------------------------------------------------------------------
__global__ __launch_bounds__(256) void k_softmax(
    const float* __restrict__ Sp, __hip_bfloat16* __restrict__ At, int nsplit,
    size_t pstride) {
  const int row = blockIdx.x * 4 + (threadIdx.x >> 6);
  const int lane = threadIdx.x & 63;
  float v[8] = {0.f, 0.f, 0.f, 0.f, 0.f, 0.f, 0.f, 0.f};
  for (int sp = 0; sp < nsplit; ++sp) {
    const float* p = Sp + sp * pstride + (size_t)row * Cx + lane * 8;
    float4 f0 = *(const float4*)p;
    float4 f1 = *(const float4*)(p + 4);
    v[0] += f0.x; v[1] += f0.y; v[2] += f0.z; v[3] += f0.w;
    v[4] += f1.x; v[5] += f1.y; v[6] += f1.z; v[7] += f1.w;
  }
  float mn = v[0];
#pragma unroll
  for (int j = 1; j < 8; ++j) mn = fminf(mn, v[j]);
#pragma unroll
  for (int off = 32; off; off >>= 1) mn = fminf(mn, __shfl_xor(mn, off));
  float w[8];
  float sum = 0.f;
#pragma unroll
  for (int j = 0; j < 8; ++j) {
    w[j] = __expf(mn - v[j]);  // <= 1, no overflow
    sum += w[j];
  }
#pragma unroll
  for (int off = 32; off; off >>= 1) sum += __shfl_xor(sum, off);
  const float inv = 1.f / sum;
  alignas(16) __hip_bfloat16 o[8];
#pragma unroll
  for (int j = 0; j < 8; ++j) o[j] = __float2bfloat16(w[j] * inv);
  *(uint4*)(At + (size_t)row * Cx + lane * 8) = *(const uint4*)o;
}

// ---------------------------------------------------------------------------
extern "C" void kernel_launch(void* const* d_in, const int* in_sizes, int n_in,
                              void* d_out, int out_size, void* d_ws,
                              size_t ws_size, hipStream_t stream) {
  const float* x = (const float*)d_in[0];
  const float* beta = (const float*)d_in[1];
  float* out = (float*)d_out;
  char* ws = (char*)d_ws;

  const size_t MB = (size_t)1 << 20;
  // ws layout: Xb 64 MiB | XbT 64 MiB | At 8 MiB.
  // Split-K partials live in d_out (134 MiB scratch until GEMM2 overwrites).
  const int nsplit = 4;
  __hip_bfloat16* xb = (__hip_bfloat16*)ws;
  __hip_bfloat16* xbt = (__hip_bfloat16*)(ws + 64 * MB);
  __hip_bfloat16* At = (__hip_bfloat16*)(ws + 128 * MB);
  float* Sp = out;
  const size_t pstride = (size_t)Bx * Cx * Cx;

  k_cast_transpose<<<dim3(Cx / 64, Nx / 64, Bx), 256, 0, stream>>>(x, xb, xbt);
  // GEMM1: S_partial[kz] = Xb * Xb^T over K-chunk kz. grid 1024 blocks.
  k_gemm_nt<false><<<(Cx / 128) * (Cx / 128) * Bx * nsplit, 256, 0, stream>>>(
      xb, xb, Sp, nullptr, nullptr, Cx, Cx, Nx, Nx / nsplit, nsplit, Cx / 128,
      Cx / 128);
  k_softmax<<<(Bx * Cx) / 4, 256, 0, stream>>>(Sp, At, nsplit, pstride);
  // GEMM2: out = beta*(attn * XbT^T) + x. grid 2048 blocks.
  k_gemm_nt<true><<<(Cx / 128) * (Nx / 128) * Bx, 256, 0, stream>>>(
      At, xbt, out, x, beta, Cx, Nx, Cx, Cx, 1, Cx / 128, Nx / 128);
}